// Round 10
// baseline (179.480 us; speedup 1.0000x reference)
//
#include <hip/hip_runtime.h>
#include <hip/hip_bf16.h>
#include <cstddef>

typedef __attribute__((ext_vector_type(8))) short short8;   // 8 x bf16
typedef __attribute__((ext_vector_type(4))) float f32x4;    // MFMA accumulator

#define MFMA16(a, b, c) __builtin_amdgcn_mfma_f32_16x16x32_bf16((a), (b), (c), 0, 0, 0)

static __device__ __forceinline__ unsigned short f2bf(float f) {   // RNE
    unsigned int u = __float_as_uint(f);
    u = (u + 0x7FFFu + ((u >> 16) & 1u)) >> 16;
    return (unsigned short)u;
}
static __device__ __forceinline__ float bf2f(unsigned short h) {
    return __uint_as_float(((unsigned int)h) << 16);
}
static __device__ __forceinline__ float silu_f(float v) { return v / (1.f + expf(-v)); }

// 8 x f32 -> 8 x bf16 fragment via v_cvt_pk_bf16_f32 (RNE; verified r5/r7)
static __device__ __forceinline__ short8 cvt_frag(const float* __restrict__ p) {
    float4 a = *reinterpret_cast<const float4*>(p);
    float4 b = *reinterpret_cast<const float4*>(p + 4);
    union { short8 s; unsigned int u[4]; } r;
    asm("v_cvt_pk_bf16_f32 %0, %1, %2" : "=v"(r.u[0]) : "v"(a.x), "v"(a.y));
    asm("v_cvt_pk_bf16_f32 %0, %1, %2" : "=v"(r.u[1]) : "v"(a.z), "v"(a.w));
    asm("v_cvt_pk_bf16_f32 %0, %1, %2" : "=v"(r.u[2]) : "v"(b.x), "v"(b.y));
    asm("v_cvt_pk_bf16_f32 %0, %1, %2" : "=v"(r.u[3]) : "v"(b.z), "v"(b.w));
    return r.s;
}

// ws layout: bf16 activations only (weights read f32 directly from d_in)
enum : size_t {
    O_XIN  = 0,                        // 512 x 1024
    O_SZ   = O_XIN  + 512 * 1024,      // 512 x 1024
    O_XDBL = O_SZ   + 512 * 1024,      // 512 x 288
    O_MOUT = O_XDBL + 512 * 288,       // 512 x 512
};

// ---------------------------------------------------------------------------
// Stage 1: xz = x @ in_proj_w^T (M=512, N=2048, K=512) + conv/silu epilogue.
// Grid (32 n-tiles, 8 m-tiles) = 256 blocks; wave = 16 rows x 64 cols.
// A (x) and B (wip) read f32 with in-register cvt.
// ---------------------------------------------------------------------------
__global__ __launch_bounds__(256, 2) void k_s1(
    const float* __restrict__ x, const float* __restrict__ wip,
    const float* __restrict__ cw, const float* __restrict__ cb,
    unsigned short* __restrict__ wsb)
{
    const int tid = threadIdx.x;
    const int w = tid >> 6, lane = tid & 63, l15 = lane & 15, g = lane >> 4;
    const int n0 = blockIdx.x * 64;
    const int m0 = blockIdx.y * 64 + w * 16;

    const float* arow = x   + (size_t)(m0 + l15) * 512 + g * 8;
    const float* brow = wip + (size_t)(n0 + l15) * 512 + g * 8;

    f32x4 acc[4] = {};
#pragma unroll 4
    for (int k0 = 0; k0 < 512; k0 += 32) {
        short8 a = cvt_frag(arow + k0);
#pragma unroll
        for (int f = 0; f < 4; ++f) {
            short8 b = cvt_frag(brow + (size_t)f * 16 * 512 + k0);
            acc[f] = MFMA16(a, b, acc[f]);
        }
    }

    const bool xhalf = (n0 < 1024);
    unsigned short* dst = wsb + (xhalf ? O_XIN : O_SZ);
#pragma unroll
    for (int f = 0; f < 4; ++f) {
        int n = n0 + f * 16 + l15;                 // global col 0..2047
        int c = xhalf ? n : n - 1024;              // col in 0..1023
        float cwv = 0.f, cbv = 0.f;
        if (xhalf) { cwv = cw[2 * n + 1]; cbv = cb[n]; }
#pragma unroll
        for (int i = 0; i < 4; ++i) {
            int r = m0 + g * 4 + i;
            float v = acc[f][i];
            v = xhalf ? silu_f(cbv + cwv * v) : silu_f(v);
            dst[(size_t)r * 1024 + c] = f2bf(v);
        }
    }
}

// ---------------------------------------------------------------------------
// Stage 2: xdbl = xin @ x_proj_w^T (M=512, N=288, K=1024).
// Grid (18 n-tiles, 8 m-tiles) = 144 blocks; wave = 16x16 tile.
// ---------------------------------------------------------------------------
__global__ __launch_bounds__(256, 2) void k_s2(
    const float* __restrict__ wxp, unsigned short* __restrict__ wsb)
{
    const int tid = threadIdx.x;
    const int w = tid >> 6, lane = tid & 63, l15 = lane & 15, g = lane >> 4;
    const int n0 = blockIdx.x * 16;
    const int m0 = blockIdx.y * 64 + w * 16;

    const unsigned short* ab = wsb + O_XIN + (size_t)(m0 + l15) * 1024 + g * 8;
    const float* brow = wxp + (size_t)(n0 + l15) * 1024 + g * 8;

    f32x4 acc = {};
#pragma unroll 4
    for (int k0 = 0; k0 < 1024; k0 += 32) {
        short8 a = *reinterpret_cast<const short8*>(ab + k0);
        short8 b = cvt_frag(brow + k0);
        acc = MFMA16(a, b, acc);
    }
    unsigned short* xd = wsb + O_XDBL;
#pragma unroll
    for (int i = 0; i < 4; ++i)
        xd[(size_t)(m0 + g * 4 + i) * 288 + n0 + l15] = f2bf(acc[i]);
}

// ---------------------------------------------------------------------------
// Stage 3+4 fused: per block (16 rows x 64 out-cols):
//   prologue: bc[r] = Bm.Cm (128 terms); dt = softplus(xdbl[:,:32]@wdt^T + b);
//             y[16][1024] = xin*(dt*bc + D)*sz  -> LDS (stride 1032: bank-safe)
//   main:     mout[16 x 64] = y_lds @ wout^T (K=1024), wout f32-direct.
// Grid (8 n-tiles, 32 m-tiles) = 256 blocks, 256 threads.
// The y-prologue is recomputed by the 8 n-blocks of each m (parallel, ~0.3us).
// ---------------------------------------------------------------------------
__global__ __launch_bounds__(256, 2) void k_s34(
    const float* __restrict__ wdt, const float* __restrict__ dtb,
    const float* __restrict__ Dv,  const float* __restrict__ wout,
    unsigned short* __restrict__ wsb)
{
    __shared__ __align__(16) unsigned short y_lds[16 * 1032];   // 33 KB
    __shared__ float bcp[16][17];
    __shared__ float bc_s[16];

    const int tid = threadIdx.x;
    const int w = tid >> 6, lane = tid & 63, l15 = lane & 15, g = lane >> 4;
    const int m0 = blockIdx.y * 16;

    const unsigned short* xd = wsb + O_XDBL;
    {   // bc[r] = sum_{s<128} Bm[r,s]*Cm[r,s]  (cols 32..159 x 160..287)
        int r = tid >> 4, p = tid & 15;
        const unsigned short* row = xd + (size_t)(m0 + r) * 288;
        float s = 0.f;
#pragma unroll
        for (int q = 0; q < 8; ++q)
            s += bf2f(row[32 + p * 8 + q]) * bf2f(row[160 + p * 8 + q]);
        bcp[r][p] = s;
    }
    short8 a3 = *reinterpret_cast<const short8*>(xd + (size_t)(m0 + l15) * 288 + g * 8);
    __syncthreads();
    if (tid < 16) {
        float s = 0.f;
#pragma unroll
        for (int p = 0; p < 16; ++p) s += bcp[tid][p];
        bc_s[tid] = s;
    }
    __syncthreads();

    // prologue: y tiles; wave w owns 16-col tiles t = w*16 .. w*16+15
    const unsigned short* xinb = wsb + O_XIN;
    const unsigned short* szb  = wsb + O_SZ;
    const f32x4 z4 = {0.f, 0.f, 0.f, 0.f};
#pragma unroll
    for (int t = 0; t < 16; ++t) {
        int n = (w * 16 + t) * 16 + l15;           // 0..1023
        short8 b = cvt_frag(wdt + (size_t)n * 32 + g * 8);
        f32x4 acc = MFMA16(a3, b, z4);
        float dtbv = dtb[n], Dvv = Dv[n];
#pragma unroll
        for (int i = 0; i < 4; ++i) {
            int r = g * 4 + i;
            float dtv = acc[i] + dtbv;
            dtv = (dtv > 20.f) ? dtv : log1pf(expf(dtv));   // softplus
            float yv = bf2f(xinb[(size_t)(m0 + r) * 1024 + n]) *
                       (dtv * bc_s[r] + Dvv) *
                       bf2f(szb[(size_t)(m0 + r) * 1024 + n]);
            y_lds[r * 1032 + n] = f2bf(yv);
        }
    }
    __syncthreads();

    // main GEMM: wave w -> out cols n0..n0+16
    const int n0 = blockIdx.x * 64 + w * 16;
    const float* brow = wout + (size_t)(n0 + l15) * 1024 + g * 8;
    f32x4 acc = {};
#pragma unroll 4
    for (int k0 = 0; k0 < 1024; k0 += 32) {
        short8 a = *reinterpret_cast<const short8*>(&y_lds[l15 * 1032 + k0 + g * 8]);
        short8 b = cvt_frag(brow + k0);
        acc = MFMA16(a, b, acc);
    }
    unsigned short* mo = wsb + O_MOUT;
#pragma unroll
    for (int i = 0; i < 4; ++i)
        mo[(size_t)(m0 + g * 4 + i) * 512 + n0 + l15] = f2bf(acc[i]);
}

// ---------------------------------------------------------------------------
// Stage 5: h1 = mout @ fc1_w^T (M=512, N=256, K=512) fused with the head:
//   out[b] = sigmoid(fc5_b + sum_j fc5_w[j] * leaky(h1[b,j] + fc1_b[j])).
// Grid 32 blocks x 512 threads; wave w = cols w*32..w*32+32; LDS reduce.
// (verified structure from r5/r7 phase E)
// ---------------------------------------------------------------------------
__global__ __launch_bounds__(512, 2) void k_s5(
    const float* __restrict__ wfc1, const float* __restrict__ bfc1,
    const float* __restrict__ wfc5, const float* __restrict__ bfc5,
    unsigned short* __restrict__ wsb, float* __restrict__ out)
{
    __shared__ float red[16][8];
    const int tid = threadIdx.x;
    const int w = tid >> 6, lane = tid & 63, l15 = lane & 15, g = lane >> 4;
    const int m0 = blockIdx.x * 16;

    const unsigned short* ab = wsb + O_MOUT + (size_t)(m0 + l15) * 512 + g * 8;
    const float* brow = wfc1 + (size_t)(w * 32 + l15) * 512 + g * 8;

    f32x4 acc[2] = {};
#pragma unroll 4
    for (int k0 = 0; k0 < 512; k0 += 32) {
        short8 a = *reinterpret_cast<const short8*>(ab + k0);
#pragma unroll
        for (int f = 0; f < 2; ++f) {
            short8 b = cvt_frag(brow + (size_t)f * 16 * 512 + k0);
            acc[f] = MFMA16(a, b, acc[f]);
        }
    }
    float part[4] = {0.f, 0.f, 0.f, 0.f};
#pragma unroll
    for (int f = 0; f < 2; ++f) {
        int n = w * 32 + f * 16 + l15;             // 0..255
        float b1 = bfc1[n], w5 = wfc5[n];
#pragma unroll
        for (int i = 0; i < 4; ++i) {
            float v = acc[f][i] + b1;
            v = v >= 0.f ? v : 0.1f * v;           // leaky relu
            part[i] = fmaf(v, w5, part[i]);
        }
    }
    // reduce across the 16 col-lanes within each k-group
#pragma unroll
    for (int off = 1; off < 16; off <<= 1)
#pragma unroll
        for (int i = 0; i < 4; ++i) part[i] += __shfl_xor(part[i], off, 64);
    if (l15 == 0)
#pragma unroll
        for (int i = 0; i < 4; ++i) red[g * 4 + i][w] = part[i];
    __syncthreads();
    if (tid < 16) {
        float s = 0.f;
#pragma unroll
        for (int j = 0; j < 8; ++j) s += red[tid][j];
        out[m0 + tid] = 1.f / (1.f + expf(-(s + bfc5[0])));
    }
}

// ---------------------------------------------------------------------------
extern "C" void kernel_launch(void* const* d_in, const int* in_sizes, int n_in,
                              void* d_out, int out_size, void* d_ws, size_t ws_size,
                              hipStream_t stream)
{
    const float* x    = (const float*)d_in[0];
    const float* wip  = (const float*)d_in[1];
    const float* cw   = (const float*)d_in[2];
    const float* cb   = (const float*)d_in[3];
    const float* wxp  = (const float*)d_in[4];
    const float* wdt  = (const float*)d_in[5];
    const float* bdt  = (const float*)d_in[6];
    // d_in[7] = A_log: unused — h0 == 0 at L==1 so dA never contributes.
    const float* Dv   = (const float*)d_in[8];
    const float* wout = (const float*)d_in[9];
    const float* wfc1 = (const float*)d_in[10];
    const float* bfc1 = (const float*)d_in[11];
    const float* wfc5 = (const float*)d_in[12];
    const float* bfc5 = (const float*)d_in[13];
    float* out = (float*)d_out;

    unsigned short* wsb = (unsigned short*)d_ws;   // bf16 activations (~3.3 MB)

    k_s1 <<<dim3(32, 8), 256, 0, stream>>>(x, wip, cw, cb, wsb);
    k_s2 <<<dim3(18, 8), 256, 0, stream>>>(wxp, wsb);
    k_s34<<<dim3(8, 32), 256, 0, stream>>>(wdt, bdt, Dv, wout, wsb);
    k_s5 <<<dim3(32),    512, 0, stream>>>(wfc1, bfc1, wfc5, bfc5, wsb, out);
}

// Round 11
// 161.802 us; speedup vs baseline: 1.1093x; 1.1093x over previous
//
#include <hip/hip_runtime.h>
#include <hip/hip_bf16.h>
#include <cstddef>

typedef __attribute__((ext_vector_type(8))) short short8;   // 8 x bf16
typedef __attribute__((ext_vector_type(4))) float f32x4;    // MFMA accumulator

#define MFMA16(a, b, c) __builtin_amdgcn_mfma_f32_16x16x32_bf16((a), (b), (c), 0, 0, 0)

static __device__ __forceinline__ unsigned short f2bf(float f) {   // RNE
    unsigned int u = __float_as_uint(f);
    u = (u + 0x7FFFu + ((u >> 16) & 1u)) >> 16;
    return (unsigned short)u;
}
static __device__ __forceinline__ float bf2f(unsigned short h) {
    return __uint_as_float(((unsigned int)h) << 16);
}
static __device__ __forceinline__ float silu_f(float v) { return v / (1.f + expf(-v)); }

// 8 x f32 -> 8 x bf16 fragment via v_cvt_pk_bf16_f32 (RNE; verified r5/r7/r10)
static __device__ __forceinline__ short8 cvt_frag(const float* __restrict__ p) {
    float4 a = *reinterpret_cast<const float4*>(p);
    float4 b = *reinterpret_cast<const float4*>(p + 4);
    union { short8 s; unsigned int u[4]; } r;
    asm("v_cvt_pk_bf16_f32 %0, %1, %2" : "=v"(r.u[0]) : "v"(a.x), "v"(a.y));
    asm("v_cvt_pk_bf16_f32 %0, %1, %2" : "=v"(r.u[1]) : "v"(a.z), "v"(a.w));
    asm("v_cvt_pk_bf16_f32 %0, %1, %2" : "=v"(r.u[2]) : "v"(b.x), "v"(b.y));
    asm("v_cvt_pk_bf16_f32 %0, %1, %2" : "=v"(r.u[3]) : "v"(b.z), "v"(b.w));
    return r.s;
}

// ws layout: bf16 activations only (weights read f32 directly from d_in)
enum : size_t {
    O_XIN  = 0,                        // 512 x 1024
    O_SZ   = O_XIN  + 512 * 1024,      // 512 x 1024
    O_XDBL = O_SZ   + 512 * 1024,      // 512 x 288
    O_Y    = O_XDBL + 512 * 288,       // 512 x 1024
    O_MOUT = O_Y    + 512 * 1024,      // 512 x 512
};

// ---------------------------------------------------------------------------
// Stage 1: xz = x @ in_proj_w^T (M=512, N=2048, K=512) + conv/silu epilogue.
// Grid (32 n-tiles, 8 m-tiles) = 256 blocks; wave = 16 rows x 64 cols.
// ---------------------------------------------------------------------------
__global__ __launch_bounds__(256, 2) void k_s1(
    const float* __restrict__ x, const float* __restrict__ wip,
    const float* __restrict__ cw, const float* __restrict__ cb,
    unsigned short* __restrict__ wsb)
{
    const int tid = threadIdx.x;
    const int w = tid >> 6, lane = tid & 63, l15 = lane & 15, g = lane >> 4;
    const int n0 = blockIdx.x * 64;
    const int m0 = blockIdx.y * 64 + w * 16;

    const float* arow = x   + (size_t)(m0 + l15) * 512 + g * 8;
    const float* brow = wip + (size_t)(n0 + l15) * 512 + g * 8;

    f32x4 acc[4] = {};
#pragma unroll 4
    for (int k0 = 0; k0 < 512; k0 += 32) {
        short8 a = cvt_frag(arow + k0);
#pragma unroll
        for (int f = 0; f < 4; ++f) {
            short8 b = cvt_frag(brow + (size_t)f * 16 * 512 + k0);
            acc[f] = MFMA16(a, b, acc[f]);
        }
    }

    const bool xhalf = (n0 < 1024);
    unsigned short* dst = wsb + (xhalf ? O_XIN : O_SZ);
#pragma unroll
    for (int f = 0; f < 4; ++f) {
        int n = n0 + f * 16 + l15;                 // global col 0..2047
        int c = xhalf ? n : n - 1024;              // col in 0..1023
        float cwv = 0.f, cbv = 0.f;
        if (xhalf) { cwv = cw[2 * n + 1]; cbv = cb[n]; }
#pragma unroll
        for (int i = 0; i < 4; ++i) {
            int r = m0 + g * 4 + i;
            float v = acc[f][i];
            v = xhalf ? silu_f(cbv + cwv * v) : silu_f(v);
            dst[(size_t)r * 1024 + c] = f2bf(v);
        }
    }
}

// ---------------------------------------------------------------------------
// Stage 2: xdbl = xin @ x_proj_w^T (M=512, N=288, K=1024).
// Grid (18 n-tiles, 8 m-tiles) = 144 blocks; wave = 16x16 tile.
// ---------------------------------------------------------------------------
__global__ __launch_bounds__(256, 2) void k_s2(
    const float* __restrict__ wxp, unsigned short* __restrict__ wsb)
{
    const int tid = threadIdx.x;
    const int w = tid >> 6, lane = tid & 63, l15 = lane & 15, g = lane >> 4;
    const int n0 = blockIdx.x * 16;
    const int m0 = blockIdx.y * 64 + w * 16;

    const unsigned short* ab = wsb + O_XIN + (size_t)(m0 + l15) * 1024 + g * 8;
    const float* brow = wxp + (size_t)(n0 + l15) * 1024 + g * 8;

    f32x4 acc = {};
#pragma unroll 4
    for (int k0 = 0; k0 < 1024; k0 += 32) {
        short8 a = *reinterpret_cast<const short8*>(ab + k0);
        short8 b = cvt_frag(brow + k0);
        acc = MFMA16(a, b, acc);
    }
    unsigned short* xd = wsb + O_XDBL;
#pragma unroll
    for (int i = 0; i < 4; ++i)
        xd[(size_t)(m0 + g * 4 + i) * 288 + n0 + l15] = f2bf(acc[i]);
}

// ---------------------------------------------------------------------------
// Stage 3: dt = softplus(xdbl[:, :32] @ dt_proj_w^T + b); bc[r] = Bm.Cm (128
// terms); y = xin * (dt*bc + D) * sz.  (M=512, N=1024, K=32)
// Grid (4 n-tiles of 256, 32 m-tiles of 16) = 128 blocks; xin/sz read ONCE.
// ---------------------------------------------------------------------------
__global__ __launch_bounds__(256, 2) void k_s3(
    const float* __restrict__ wdt, const float* __restrict__ dtb,
    const float* __restrict__ Dv,  unsigned short* __restrict__ wsb)
{
    __shared__ float bcp[16][17];
    __shared__ float bc_s[16];
    const int tid = threadIdx.x;
    const int w = tid >> 6, lane = tid & 63, l15 = lane & 15, g = lane >> 4;
    const int n0 = blockIdx.x * 256;
    const int m0 = blockIdx.y * 16;

    const unsigned short* xd = wsb + O_XDBL;
    {   // bc[r] = sum_{s<128} Bm[r,s]*Cm[r,s]  (cols 32..159 x 160..287)
        int r = tid >> 4, p = tid & 15;
        const unsigned short* row = xd + (size_t)(m0 + r) * 288;
        float s = 0.f;
#pragma unroll
        for (int q = 0; q < 8; ++q)
            s += bf2f(row[32 + p * 8 + q]) * bf2f(row[160 + p * 8 + q]);
        bcp[r][p] = s;
    }
    short8 a = *reinterpret_cast<const short8*>(xd + (size_t)(m0 + l15) * 288 + g * 8);
    __syncthreads();
    if (tid < 16) {
        float s = 0.f;
#pragma unroll
        for (int p = 0; p < 16; ++p) s += bcp[tid][p];
        bc_s[tid] = s;
    }
    __syncthreads();

    const unsigned short* xinb = wsb + O_XIN;
    const unsigned short* szb  = wsb + O_SZ;
    unsigned short* yb = wsb + O_Y;
    const f32x4 z4 = {0.f, 0.f, 0.f, 0.f};
#pragma unroll
    for (int f = 0; f < 4; ++f) {
        int n = n0 + w * 64 + f * 16 + l15;        // 0..1023
        short8 b = cvt_frag(wdt + (size_t)n * 32 + g * 8);
        f32x4 acc = MFMA16(a, b, z4);
        float dtbv = dtb[n], Dvv = Dv[n];
#pragma unroll
        for (int i = 0; i < 4; ++i) {
            int r = m0 + g * 4 + i;
            float dtv = acc[i] + dtbv;
            dtv = (dtv > 20.f) ? dtv : log1pf(expf(dtv));   // softplus
            float yv = bf2f(xinb[(size_t)r * 1024 + n]) *
                       (dtv * bc_s[g * 4 + i] + Dvv) *
                       bf2f(szb[(size_t)r * 1024 + n]);
            yb[(size_t)r * 1024 + n] = f2bf(yv);
        }
    }
}

// ---------------------------------------------------------------------------
// Stage 4: mout = y @ out_proj_w^T (M=512, N=512, K=1024).
// Grid (8 n-tiles of 64, 32 m-tiles of 16) = 256 blocks; wave = 16x16 tile.
// Fixed n -> every 8th linear id -> one XCD per n-slice (wout fetched once).
// ---------------------------------------------------------------------------
__global__ __launch_bounds__(256, 2) void k_s4(
    const float* __restrict__ wout, unsigned short* __restrict__ wsb)
{
    const int tid = threadIdx.x;
    const int w = tid >> 6, lane = tid & 63, l15 = lane & 15, g = lane >> 4;
    const int n0 = blockIdx.x * 64 + w * 16;
    const int m0 = blockIdx.y * 16;

    const unsigned short* ab = wsb + O_Y + (size_t)(m0 + l15) * 1024 + g * 8;
    const float* brow = wout + (size_t)(n0 + l15) * 1024 + g * 8;

    f32x4 acc = {};
#pragma unroll 4
    for (int k0 = 0; k0 < 1024; k0 += 32) {
        short8 a = *reinterpret_cast<const short8*>(ab + k0);
        short8 b = cvt_frag(brow + k0);
        acc = MFMA16(a, b, acc);
    }
    unsigned short* mo = wsb + O_MOUT;
#pragma unroll
    for (int i = 0; i < 4; ++i)
        mo[(size_t)(m0 + g * 4 + i) * 512 + n0 + l15] = f2bf(acc[i]);
}

// ---------------------------------------------------------------------------
// Stage 5: h1 = mout @ fc1_w^T (M=512, N=256, K=512) fused with the head:
//   out[b] = sigmoid(fc5_b + sum_j fc5_w[j] * leaky(h1[b,j] + fc1_b[j])).
// Grid 32 blocks x 512 threads; wave w = cols w*32..w*32+32; LDS reduce.
// ---------------------------------------------------------------------------
__global__ __launch_bounds__(512, 2) void k_s5(
    const float* __restrict__ wfc1, const float* __restrict__ bfc1,
    const float* __restrict__ wfc5, const float* __restrict__ bfc5,
    unsigned short* __restrict__ wsb, float* __restrict__ out)
{
    __shared__ float red[16][8];
    const int tid = threadIdx.x;
    const int w = tid >> 6, lane = tid & 63, l15 = lane & 15, g = lane >> 4;
    const int m0 = blockIdx.x * 16;

    const unsigned short* ab = wsb + O_MOUT + (size_t)(m0 + l15) * 512 + g * 8;
    const float* brow = wfc1 + (size_t)(w * 32 + l15) * 512 + g * 8;

    f32x4 acc[2] = {};
#pragma unroll 4
    for (int k0 = 0; k0 < 512; k0 += 32) {
        short8 a = *reinterpret_cast<const short8*>(ab + k0);
#pragma unroll
        for (int f = 0; f < 2; ++f) {
            short8 b = cvt_frag(brow + (size_t)f * 16 * 512 + k0);
            acc[f] = MFMA16(a, b, acc[f]);
        }
    }
    float part[4] = {0.f, 0.f, 0.f, 0.f};
#pragma unroll
    for (int f = 0; f < 2; ++f) {
        int n = w * 32 + f * 16 + l15;             // 0..255
        float b1 = bfc1[n], w5 = wfc5[n];
#pragma unroll
        for (int i = 0; i < 4; ++i) {
            float v = acc[f][i] + b1;
            v = v >= 0.f ? v : 0.1f * v;           // leaky relu
            part[i] = fmaf(v, w5, part[i]);
        }
    }
    // reduce across the 16 col-lanes within each k-group
#pragma unroll
    for (int off = 1; off < 16; off <<= 1)
#pragma unroll
        for (int i = 0; i < 4; ++i) part[i] += __shfl_xor(part[i], off, 64);
    if (l15 == 0)
#pragma unroll
        for (int i = 0; i < 4; ++i) red[g * 4 + i][w] = part[i];
    __syncthreads();
    if (tid < 16) {
        float s = 0.f;
#pragma unroll
        for (int j = 0; j < 8; ++j) s += red[tid][j];
        out[m0 + tid] = 1.f / (1.f + expf(-(s + bfc5[0])));
    }
}

// ---------------------------------------------------------------------------
extern "C" void kernel_launch(void* const* d_in, const int* in_sizes, int n_in,
                              void* d_out, int out_size, void* d_ws, size_t ws_size,
                              hipStream_t stream)
{
    const float* x    = (const float*)d_in[0];
    const float* wip  = (const float*)d_in[1];
    const float* cw   = (const float*)d_in[2];
    const float* cb   = (const float*)d_in[3];
    const float* wxp  = (const float*)d_in[4];
    const float* wdt  = (const float*)d_in[5];
    const float* bdt  = (const float*)d_in[6];
    // d_in[7] = A_log: unused — h0 == 0 at L==1 so dA never contributes.
    const float* Dv   = (const float*)d_in[8];
    const float* wout = (const float*)d_in[9];
    const float* wfc1 = (const float*)d_in[10];
    const float* bfc1 = (const float*)d_in[11];
    const float* wfc5 = (const float*)d_in[12];
    const float* bfc5 = (const float*)d_in[13];
    float* out = (float*)d_out;

    unsigned short* wsb = (unsigned short*)d_ws;   // bf16 activations (~4.3 MB)

    k_s1<<<dim3(32, 8), 256, 0, stream>>>(x, wip, cw, cb, wsb);
    k_s2<<<dim3(18, 8), 256, 0, stream>>>(wxp, wsb);
    k_s3<<<dim3(4, 32), 256, 0, stream>>>(wdt, bdt, Dv, wsb);
    k_s4<<<dim3(8, 32), 256, 0, stream>>>(wout, wsb);
    k_s5<<<dim3(32),    512, 0, stream>>>(wfc1, bfc1, wfc5, bfc5, wsb, out);
}

// Round 12
// 142.202 us; speedup vs baseline: 1.2622x; 1.1378x over previous
//
#include <hip/hip_runtime.h>
#include <hip/hip_bf16.h>
#include <cstddef>

typedef __attribute__((ext_vector_type(8))) short short8;   // 8 x bf16
typedef __attribute__((ext_vector_type(4))) float f32x4;    // MFMA accumulator

#define MFMA16(a, b, c) __builtin_amdgcn_mfma_f32_16x16x32_bf16((a), (b), (c), 0, 0, 0)

static __device__ __forceinline__ unsigned short f2bf(float f) {   // RNE
    unsigned int u = __float_as_uint(f);
    u = (u + 0x7FFFu + ((u >> 16) & 1u)) >> 16;
    return (unsigned short)u;
}
static __device__ __forceinline__ float bf2f(unsigned short h) {
    return __uint_as_float(((unsigned int)h) << 16);
}
static __device__ __forceinline__ float silu_f(float v) { return v / (1.f + expf(-v)); }

// 8 x f32 -> 8 x bf16 fragment via v_cvt_pk_bf16_f32 (RNE; verified r5-r11)
static __device__ __forceinline__ short8 cvt_frag(const float* __restrict__ p) {
    float4 a = *reinterpret_cast<const float4*>(p);
    float4 b = *reinterpret_cast<const float4*>(p + 4);
    union { short8 s; unsigned int u[4]; } r;
    asm("v_cvt_pk_bf16_f32 %0, %1, %2" : "=v"(r.u[0]) : "v"(a.x), "v"(a.y));
    asm("v_cvt_pk_bf16_f32 %0, %1, %2" : "=v"(r.u[1]) : "v"(a.z), "v"(a.w));
    asm("v_cvt_pk_bf16_f32 %0, %1, %2" : "=v"(r.u[2]) : "v"(b.x), "v"(b.y));
    asm("v_cvt_pk_bf16_f32 %0, %1, %2" : "=v"(r.u[3]) : "v"(b.z), "v"(b.w));
    return r.s;
}

// ws layout, bf16-element offsets (all multiples of 8 -> 16B aligned)
enum : size_t {
    O_X     = 0,                        // 512 x 512
    O_WIP   = O_X    + 512 * 512,       // 2048 x 512
    O_WXP   = O_WIP  + 2048 * 512,      // 288 x 1024
    O_WDT   = O_WXP  + 288 * 1024,      // 1024 x 32
    O_WOUT  = O_WDT  + 1024 * 32,       // 512 x 1024
    O_WFC1  = O_WOUT + 512 * 1024,      // 256 x 512
    O_XIN   = O_WFC1 + 256 * 512,       // 512 x 1024 (bf16 act)
    O_SZ    = O_XIN  + 512 * 1024,      // 512 x 1024
    O_Y     = O_SZ   + 512 * 1024,      // 512 x 1024
    O_F32   = O_Y    + 512 * 1024,      // f32 split-K accumulators below
};
#define N_XDBLF (512 * 288)             // f32
#define N_MOUTF (512 * 512)             // f32
#define N_ZERO  (N_XDBLF + N_MOUTF)

// ---------------------------------------------------------------------------
// k_convert: stage x + 5 weights f32->bf16 once; zero the split-K f32 accs.
// ---------------------------------------------------------------------------
static __device__ __forceinline__ void cvt_seg(const float* __restrict__ s,
                                               unsigned short* __restrict__ d,
                                               int n, int gt, int np)
{
    for (int i = gt * 4; i < n; i += np * 4) {
        float4 v = *reinterpret_cast<const float4*>(s + i);
        ushort4 o;
        o.x = f2bf(v.x); o.y = f2bf(v.y); o.z = f2bf(v.z); o.w = f2bf(v.w);
        *reinterpret_cast<ushort4*>(d + i) = o;
    }
}

__global__ __launch_bounds__(256) void k_convert(
    const float* __restrict__ x,    const float* __restrict__ wip,
    const float* __restrict__ wxp,  const float* __restrict__ wdt,
    const float* __restrict__ wout, const float* __restrict__ wfc1,
    unsigned short* __restrict__ wsb)
{
    const int gt = blockIdx.x * blockDim.x + threadIdx.x;
    const int np = gridDim.x * blockDim.x;
    cvt_seg(x,    wsb + O_X,    512 * 512,  gt, np);
    cvt_seg(wip,  wsb + O_WIP,  2048 * 512, gt, np);
    cvt_seg(wxp,  wsb + O_WXP,  288 * 1024, gt, np);
    cvt_seg(wdt,  wsb + O_WDT,  1024 * 32,  gt, np);
    cvt_seg(wout, wsb + O_WOUT, 512 * 1024, gt, np);
    cvt_seg(wfc1, wsb + O_WFC1, 256 * 512,  gt, np);
    float* z = (float*)(wsb + O_F32);
    const float4 z4 = make_float4(0.f, 0.f, 0.f, 0.f);
    for (int i = gt * 4; i < N_ZERO; i += np * 4)
        *reinterpret_cast<float4*>(z + i) = z4;
}

// ---------------------------------------------------------------------------
// Stage 1: xz = x @ wip^T (M=512,N=2048,K=512) + conv/silu.
// Grid (32,32) = 1024 blocks (4/CU, 16 waves/CU); wave = one 16x16 tile.
// ---------------------------------------------------------------------------
__global__ __launch_bounds__(256, 4) void k_s1(
    unsigned short* __restrict__ wsb,
    const float* __restrict__ cw, const float* __restrict__ cb)
{
    const int tid = threadIdx.x;
    const int w = tid >> 6, lane = tid & 63, l15 = lane & 15, g = lane >> 4;
    const int n0 = blockIdx.x * 64 + w * 16;
    const int m0 = blockIdx.y * 16;

    const unsigned short* arow = wsb + O_X   + (size_t)(m0 + l15) * 512 + g * 8;
    const unsigned short* brow = wsb + O_WIP + (size_t)(n0 + l15) * 512 + g * 8;

    f32x4 acc = {};
#pragma unroll 4
    for (int k0 = 0; k0 < 512; k0 += 32) {
        short8 a = *reinterpret_cast<const short8*>(arow + k0);
        short8 b = *reinterpret_cast<const short8*>(brow + k0);
        acc = MFMA16(a, b, acc);
    }
    const bool xhalf = (blockIdx.x < 16);
    unsigned short* dst = wsb + (xhalf ? O_XIN : O_SZ);
    int n = n0 + l15;                              // 0..2047
    int c = xhalf ? n : n - 1024;
    float cwv = 0.f, cbv = 0.f;
    if (xhalf) { cwv = cw[2 * n + 1]; cbv = cb[n]; }
#pragma unroll
    for (int i = 0; i < 4; ++i) {
        float v = acc[i];
        v = xhalf ? silu_f(cbv + cwv * v) : silu_f(v);
        dst[(size_t)(m0 + g * 4 + i) * 1024 + c] = f2bf(v);
    }
}

// ---------------------------------------------------------------------------
// Stage 2: xdbl_f32 += xin @ wxp^T (M=512,N=288,K=1024), split-K x4.
// Grid (18,8,4) = 576 blocks (2.25/CU); block = 64 rows x 16 cols.
// ---------------------------------------------------------------------------
__global__ __launch_bounds__(256, 4) void k_s2(
    unsigned short* __restrict__ wsb, float* __restrict__ xdblf)
{
    const int tid = threadIdx.x;
    const int w = tid >> 6, lane = tid & 63, l15 = lane & 15, g = lane >> 4;
    const int n0 = blockIdx.x * 16;
    const int m0 = blockIdx.y * 64 + w * 16;
    const int kq = blockIdx.z * 256;

    const unsigned short* arow = wsb + O_XIN + (size_t)(m0 + l15) * 1024 + kq + g * 8;
    const unsigned short* brow = wsb + O_WXP + (size_t)(n0 + l15) * 1024 + kq + g * 8;

    f32x4 acc = {};
#pragma unroll 4
    for (int k0 = 0; k0 < 256; k0 += 32) {
        short8 a = *reinterpret_cast<const short8*>(arow + k0);
        short8 b = *reinterpret_cast<const short8*>(brow + k0);
        acc = MFMA16(a, b, acc);
    }
#pragma unroll
    for (int i = 0; i < 4; ++i)
        atomicAdd(&xdblf[(size_t)(m0 + g * 4 + i) * 288 + n0 + l15], acc[i]);
}

// ---------------------------------------------------------------------------
// Stage 3: bc[r] = Bm.Cm (f32, 128 terms); dt = softplus(xdbl[:,:32]@wdt^T+b);
//          y = xin * (dt*bc + D) * sz.
// Grid (16,32) = 512 blocks (2/CU); wave = one 16x16 tile of y.
// ---------------------------------------------------------------------------
__global__ __launch_bounds__(256, 4) void k_s3(
    unsigned short* __restrict__ wsb, const float* __restrict__ xdblf,
    const float* __restrict__ dtb, const float* __restrict__ Dv)
{
    __shared__ float bcp[16][17];
    __shared__ float bc_s[16];
    const int tid = threadIdx.x;
    const int w = tid >> 6, lane = tid & 63, l15 = lane & 15, g = lane >> 4;
    const int n0 = blockIdx.x * 64;
    const int m0 = blockIdx.y * 16;

    {   // bc[r] = sum_{s<128} Bm[r,s]*Cm[r,s]  (f32 rows of xdbl)
        int r = tid >> 4, p = tid & 15;
        const float* row = xdblf + (size_t)(m0 + r) * 288;
        float s = 0.f;
#pragma unroll
        for (int q = 0; q < 8; ++q)
            s += row[32 + p * 8 + q] * row[160 + p * 8 + q];
        bcp[r][p] = s;
    }
    short8 a3 = cvt_frag(xdblf + (size_t)(m0 + l15) * 288 + g * 8);   // cols 0..31
    __syncthreads();
    if (tid < 16) {
        float s = 0.f;
#pragma unroll
        for (int p = 0; p < 16; ++p) s += bcp[tid][p];
        bc_s[tid] = s;
    }
    __syncthreads();

    const unsigned short* xinb = wsb + O_XIN;
    const unsigned short* szb  = wsb + O_SZ;
    unsigned short* yb = wsb + O_Y;
    const f32x4 z4 = {0.f, 0.f, 0.f, 0.f};
    int n = n0 + w * 16 + l15;                     // 0..1023
    short8 b = *reinterpret_cast<const short8*>(wsb + O_WDT + (size_t)n * 32 + g * 8);
    f32x4 acc = MFMA16(a3, b, z4);
    float dtbv = dtb[n], Dvv = Dv[n];
#pragma unroll
    for (int i = 0; i < 4; ++i) {
        int r = m0 + g * 4 + i;
        float dtv = acc[i] + dtbv;
        dtv = (dtv > 20.f) ? dtv : log1pf(expf(dtv));   // softplus
        float yv = bf2f(xinb[(size_t)r * 1024 + n]) *
                   (dtv * bc_s[g * 4 + i] + Dvv) *
                   bf2f(szb[(size_t)r * 1024 + n]);
        yb[(size_t)r * 1024 + n] = f2bf(yv);
    }
}

// ---------------------------------------------------------------------------
// Stage 4: mout_f32 += y @ wout^T (M=512,N=512,K=1024), split-K x2.
// Grid (8,32,2) = 512 blocks (2/CU); block = 16 rows x 64 cols.
// ---------------------------------------------------------------------------
__global__ __launch_bounds__(256, 4) void k_s4(
    unsigned short* __restrict__ wsb, float* __restrict__ moutf)
{
    const int tid = threadIdx.x;
    const int w = tid >> 6, lane = tid & 63, l15 = lane & 15, g = lane >> 4;
    const int n0 = blockIdx.x * 64 + w * 16;
    const int m0 = blockIdx.y * 16;
    const int kq = blockIdx.z * 512;

    const unsigned short* arow = wsb + O_Y    + (size_t)(m0 + l15) * 1024 + kq + g * 8;
    const unsigned short* brow = wsb + O_WOUT + (size_t)(n0 + l15) * 1024 + kq + g * 8;

    f32x4 acc = {};
#pragma unroll 4
    for (int k0 = 0; k0 < 512; k0 += 32) {
        short8 a = *reinterpret_cast<const short8*>(arow + k0);
        short8 b = *reinterpret_cast<const short8*>(brow + k0);
        acc = MFMA16(a, b, acc);
    }
#pragma unroll
    for (int i = 0; i < 4; ++i)
        atomicAdd(&moutf[(size_t)(m0 + g * 4 + i) * 512 + n0 + l15], acc[i]);
}

// ---------------------------------------------------------------------------
// Stage 5: h1 = mout @ fc1_w^T (M=512,N=256,K=512) + head.
// Grid 32 x 512 thr (8 waves/CU on 32 CUs); A f32 via cvt_frag, B staged bf16.
// ---------------------------------------------------------------------------
__global__ __launch_bounds__(512, 2) void k_s5(
    const float* __restrict__ moutf, unsigned short* __restrict__ wsb,
    const float* __restrict__ bfc1, const float* __restrict__ wfc5,
    const float* __restrict__ bfc5, float* __restrict__ out)
{
    __shared__ float red[16][8];
    const int tid = threadIdx.x;
    const int w = tid >> 6, lane = tid & 63, l15 = lane & 15, g = lane >> 4;
    const int m0 = blockIdx.x * 16;

    const float* arow = moutf + (size_t)(m0 + l15) * 512 + g * 8;
    const unsigned short* brow = wsb + O_WFC1 + (size_t)(w * 32 + l15) * 512 + g * 8;

    f32x4 acc[2] = {};
#pragma unroll 4
    for (int k0 = 0; k0 < 512; k0 += 32) {
        short8 a = cvt_frag(arow + k0);
#pragma unroll
        for (int f = 0; f < 2; ++f) {
            short8 b = *reinterpret_cast<const short8*>(brow + (size_t)f * 16 * 512 + k0);
            acc[f] = MFMA16(a, b, acc[f]);
        }
    }
    float part[4] = {0.f, 0.f, 0.f, 0.f};
#pragma unroll
    for (int f = 0; f < 2; ++f) {
        int n = w * 32 + f * 16 + l15;             // 0..255
        float b1 = bfc1[n], w5 = wfc5[n];
#pragma unroll
        for (int i = 0; i < 4; ++i) {
            float v = acc[f][i] + b1;
            v = v >= 0.f ? v : 0.1f * v;           // leaky relu
            part[i] = fmaf(v, w5, part[i]);
        }
    }
#pragma unroll
    for (int off = 1; off < 16; off <<= 1)
#pragma unroll
        for (int i = 0; i < 4; ++i) part[i] += __shfl_xor(part[i], off, 64);
    if (l15 == 0)
#pragma unroll
        for (int i = 0; i < 4; ++i) red[g * 4 + i][w] = part[i];
    __syncthreads();
    if (tid < 16) {
        float s = 0.f;
#pragma unroll
        for (int j = 0; j < 8; ++j) s += red[tid][j];
        out[m0 + tid] = 1.f / (1.f + expf(-(s + bfc5[0])));
    }
}

// ---------------------------------------------------------------------------
extern "C" void kernel_launch(void* const* d_in, const int* in_sizes, int n_in,
                              void* d_out, int out_size, void* d_ws, size_t ws_size,
                              hipStream_t stream)
{
    const float* x    = (const float*)d_in[0];
    const float* wip  = (const float*)d_in[1];
    const float* cw   = (const float*)d_in[2];
    const float* cb   = (const float*)d_in[3];
    const float* wxp  = (const float*)d_in[4];
    const float* wdt  = (const float*)d_in[5];
    const float* bdt  = (const float*)d_in[6];
    // d_in[7] = A_log: unused — h0 == 0 at L==1 so dA never contributes.
    const float* Dv   = (const float*)d_in[8];
    const float* wout = (const float*)d_in[9];
    const float* wfc1 = (const float*)d_in[10];
    const float* bfc1 = (const float*)d_in[11];
    const float* wfc5 = (const float*)d_in[12];
    const float* bfc5 = (const float*)d_in[13];
    float* out = (float*)d_out;

    unsigned short* wsb = (unsigned short*)d_ws;
    float* xdblf = (float*)(wsb + O_F32);
    float* moutf = xdblf + N_XDBLF;

    k_convert<<<dim3(1024),    256, 0, stream>>>(x, wip, wxp, wdt, wout, wfc1, wsb);
    k_s1     <<<dim3(32, 32),  256, 0, stream>>>(wsb, cw, cb);
    k_s2     <<<dim3(18, 8, 4),256, 0, stream>>>(wsb, xdblf);
    k_s3     <<<dim3(16, 32),  256, 0, stream>>>(wsb, xdblf, bdt, Dv);
    k_s4     <<<dim3(8, 32, 2),256, 0, stream>>>(wsb, moutf);
    k_s5     <<<dim3(32),      512, 0, stream>>>(moutf, wsb, bfc1, wfc5, bfc5, out);
}